// Round 2
// baseline (182.143 us; speedup 1.0000x reference)
//
#include <hip/hip_runtime.h>

// MaxUnpooling2D: x [B=16, H=64, W=64, C=128] f32, index int32 on device
// (harness casts integer inputs to int32; values < 2^25 so no loss).
// Collision-free: each pooled elem (b,h,w,c) maps into its own 2x2 block of
// the [B, 2H, 2W, C] output. One thread per 4 consecutive channels writes all
// 4 cells of the 2x2 block (value to the chosen cell, zeros to the rest) ->
// covers every output element exactly once, no memset pass, no atomics.

#define B_ 16
#define H_ 64
#define W_ 64
#define C_ 128
// output row stride (floats): 2W * C = 16384 = 1<<14
// output col stride (floats): C = 128 = 1<<7

__global__ __launch_bounds__(256) void unpool_kernel(
    const float4* __restrict__ x,
    const int4* __restrict__ idx,
    float4* __restrict__ out,
    int n_groups)
{
    int g = blockIdx.x * blockDim.x + threadIdx.x;   // group of 4 channels
    if (g >= n_groups) return;

    // decompose group index: c4 in [0,32), w in [0,64), h in [0,64), b in [0,16)
    int c4 = g & 31;
    int w  = (g >> 5) & 63;
    int h  = (g >> 11) & 63;
    int b  = g >> 17;

    float4 xv = x[g];
    int4   iv = idx[g];

    // chosen cell k = dh*2 + dw, extracted straight from the flat index:
    // dh = (idx >> 14) & 1, dw = (idx >> 7) & 1
    int k0 = (((iv.x >> 14) & 1) << 1) | ((iv.x >> 7) & 1);
    int k1 = (((iv.y >> 14) & 1) << 1) | ((iv.y >> 7) & 1);
    int k2 = (((iv.z >> 14) & 1) << 1) | ((iv.z >> 7) & 1);
    int k3 = (((iv.w >> 14) & 1) << 1) | ((iv.w >> 7) & 1);

    // base output element offset of cell (0,0): out[b][2h][2w][c4*4]
    int base = ((b * (2 * H_) + 2 * h) * (2 * W_) + 2 * w) * C_ + c4 * 4;
    float4* o = out + (base >> 2);   // float4 units; base is 16B aligned

    // float4-unit offsets of the 4 cells: (0,0)=0, (0,1)=C/4=32,
    // (1,0)=2W*C/4=4096, (1,1)=4128
    const int off[4] = {0, 32, 4096, 4128};

#pragma unroll
    for (int k = 0; k < 4; ++k) {
        float4 v;
        v.x = (k0 == k) ? xv.x : 0.0f;
        v.y = (k1 == k) ? xv.y : 0.0f;
        v.z = (k2 == k) ? xv.z : 0.0f;
        v.w = (k3 == k) ? xv.w : 0.0f;
        o[off[k]] = v;
    }
}

extern "C" void kernel_launch(void* const* d_in, const int* in_sizes, int n_in,
                              void* d_out, int out_size, void* d_ws, size_t ws_size,
                              hipStream_t stream) {
    const float4* x   = (const float4*)d_in[0];
    const int4*   idx = (const int4*)d_in[1];
    float4*       out = (float4*)d_out;

    int n_elems  = in_sizes[0];          // 8,388,608
    int n_groups = n_elems / 4;          // 2,097,152
    int block = 256;
    int grid = (n_groups + block - 1) / block;   // 8192

    unpool_kernel<<<grid, block, 0, stream>>>(x, idx, out, n_groups);
}

// Round 4
// 178.502 us; speedup vs baseline: 1.0204x; 1.0204x over previous
//
#include <hip/hip_runtime.h>

// MaxUnpooling2D: x [B=16, H=64, W=64, C=128] f32, index int32 on device.
// Collision-free: each pooled elem (b,h,w,c) owns its 2x2 block of the
// [B, 2H, 2W, C] output. One thread per 4 consecutive channels writes all
// 4 cells of the block (value to chosen cell, zeros elsewhere) -> every
// output element written exactly once, no memset pass, no atomics.
//
// R3: nontemporal hints via clang ext_vector_type (HIP_vector_type structs
// are rejected by __builtin_nontemporal_*).

#define B_ 16
#define H_ 64
#define W_ 64
#define C_ 128
// output row stride (floats): 2W * C = 16384 = 1<<14
// output col stride (floats): C = 128 = 1<<7

typedef float f32x4 __attribute__((ext_vector_type(4)));
typedef int   i32x4 __attribute__((ext_vector_type(4)));

__global__ __launch_bounds__(256) void unpool_kernel(
    const f32x4* __restrict__ x,
    const i32x4* __restrict__ idx,
    f32x4* __restrict__ out,
    int n_groups)
{
    int g = blockIdx.x * blockDim.x + threadIdx.x;   // group of 4 channels
    if (g >= n_groups) return;

    // decompose: c4 in [0,32), w in [0,64), h in [0,64), b in [0,16)
    int c4 = g & 31;
    int w  = (g >> 5) & 63;
    int h  = (g >> 11) & 63;
    int b  = g >> 17;

    f32x4 xv = __builtin_nontemporal_load(&x[g]);
    i32x4 iv = __builtin_nontemporal_load(&idx[g]);

    // chosen cell k = dh*2 + dw from the flat index:
    // dh = (idx >> 14) & 1, dw = (idx >> 7) & 1
    int k0 = (((iv.x >> 14) & 1) << 1) | ((iv.x >> 7) & 1);
    int k1 = (((iv.y >> 14) & 1) << 1) | ((iv.y >> 7) & 1);
    int k2 = (((iv.z >> 14) & 1) << 1) | ((iv.z >> 7) & 1);
    int k3 = (((iv.w >> 14) & 1) << 1) | ((iv.w >> 7) & 1);

    // base output element offset of cell (0,0): out[b][2h][2w][c4*4]
    int base = ((b * (2 * H_) + 2 * h) * (2 * W_) + 2 * w) * C_ + c4 * 4;
    f32x4* o = out + (base >> 2);   // f32x4 units; 16B aligned

    // f32x4-unit offsets of the 4 cells: (0,0)=0, (0,1)=C/4=32,
    // (1,0)=2W*C/4=4096, (1,1)=4128
    const int off[4] = {0, 32, 4096, 4128};

#pragma unroll
    for (int k = 0; k < 4; ++k) {
        f32x4 v;
        v.x = (k0 == k) ? xv.x : 0.0f;
        v.y = (k1 == k) ? xv.y : 0.0f;
        v.z = (k2 == k) ? xv.z : 0.0f;
        v.w = (k3 == k) ? xv.w : 0.0f;
        __builtin_nontemporal_store(v, &o[off[k]]);
    }
}

extern "C" void kernel_launch(void* const* d_in, const int* in_sizes, int n_in,
                              void* d_out, int out_size, void* d_ws, size_t ws_size,
                              hipStream_t stream) {
    const f32x4* x   = (const f32x4*)d_in[0];
    const i32x4* idx = (const i32x4*)d_in[1];
    f32x4*       out = (f32x4*)d_out;

    int n_elems  = in_sizes[0];          // 8,388,608
    int n_groups = n_elems / 4;          // 2,097,152
    int block = 256;
    int grid = (n_groups + block - 1) / block;   // 8192

    unpool_kernel<<<grid, block, 0, stream>>>(x, idx, out, n_groups);
}